// Round 6
// baseline (201.064 us; speedup 1.0000x reference)
//
#include <hip/hip_runtime.h>

// DIAGNOSTIC ROUND: identical RBF kernel launched 3x. dur_us delta vs the
// single-launch round (148.5 us) = 2*K where K = true per-dispatch time.
// Writes are idempotent -> correctness unaffected.
//
// RBF: out[b, n, 0] = exp(-||x[b] - c[n]||^2 / 0.04)
//      out[b, n, 1] = exp(-||x_delayed[b] - c[n]||^2 / 0.04)
// exp(-d/beta) = exp2(d * (-log2(e)/beta)); beta = 0.04
#define EXP2_SCALE (-36.06737602222409f)   // -log2(e) / 0.04

#define N_RBF      8192
#define NPAIR      (N_RBF / 2)             // 4096 float4 per b-row
#define BLOCK      256
#define ITERS      (NPAIR / BLOCK)         // 16

// Native vector type: __builtin_nontemporal_store rejects HIP_vector_type.
typedef float f32x4 __attribute__((ext_vector_type(4)));

__global__ __launch_bounds__(BLOCK) void rbf_kernel(
    const float2* __restrict__ x,        // [B]
    const float2* __restrict__ xd,       // [B]
    const f32x4* __restrict__ c4,        // [N/2] (two centres per f32x4)
    f32x4* __restrict__ out)             // [B * N/2]
{
    const int b = blockIdx.x;            // one b-row per block
    const float2 xb  = x[b];             // block-uniform -> s_load, once
    const float2 xdb = xd[b];
    const int t = threadIdx.x;
    f32x4* __restrict__ orow = out + (size_t)b * NPAIR;

    #pragma unroll 8
    for (int i = 0; i < ITERS; ++i) {
        const int nn = i * BLOCK + t;
        const f32x4 cc = c4[nn];         // coalesced 16B/lane, L2-resident

        float dx, dy;
        dx = xb.x  - cc.x;  dy = xb.y  - cc.y;  const float d00 = dx*dx + dy*dy;
        dx = xdb.x - cc.x;  dy = xdb.y - cc.y;  const float d01 = dx*dx + dy*dy;
        dx = xb.x  - cc.z;  dy = xb.y  - cc.w;  const float d10 = dx*dx + dy*dy;
        dx = xdb.x - cc.z;  dy = xdb.y - cc.w;  const float d11 = dx*dx + dy*dy;

        f32x4 o;
        o.x = __builtin_amdgcn_exp2f(d00 * EXP2_SCALE);
        o.y = __builtin_amdgcn_exp2f(d01 * EXP2_SCALE);
        o.z = __builtin_amdgcn_exp2f(d10 * EXP2_SCALE);
        o.w = __builtin_amdgcn_exp2f(d11 * EXP2_SCALE);

        __builtin_nontemporal_store(o, &orow[nn]);
    }
}

extern "C" void kernel_launch(void* const* d_in, const int* in_sizes, int n_in,
                              void* d_out, int out_size, void* d_ws, size_t ws_size,
                              hipStream_t stream) {
    const float2* x  = (const float2*)d_in[0];   // [B,2] fp32
    const float2* xd = (const float2*)d_in[1];   // [B,2] fp32
    const f32x4* c4  = (const f32x4*)d_in[2];    // [N,2] fp32 as [N/2] f32x4
    f32x4* out = (f32x4*)d_out;                  // [B,N,2] fp32 as f32x4

    const int B = in_sizes[0] / 2;               // 2048

    // 3 identical, idempotent dispatches: dur_us = fixed + 3K (was fixed + K).
    rbf_kernel<<<B, BLOCK, 0, stream>>>(x, xd, c4, out);
    rbf_kernel<<<B, BLOCK, 0, stream>>>(x, xd, c4, out);
    rbf_kernel<<<B, BLOCK, 0, stream>>>(x, xd, c4, out);
}

// Round 7
// 144.130 us; speedup vs baseline: 1.3950x; 1.3950x over previous
//
#include <hip/hip_runtime.h>

// RBF: out[b, n, 0] = exp(-||x[b] - c[n]||^2 / 0.04)
//      out[b, n, 1] = exp(-||x_delayed[b] - c[n]||^2 / 0.04)
// B = 2048, N = 8192, out = [B, N, 2] fp32 (128 MiB).
//
// Measured (R6 3x-launch diagnostic): true kernel time K ~= 26.3 us
// (5.1 TB/s); dur_us carries ~122 us of fixed harness resets.
//
// This round's single variable: PLAIN stores instead of nontemporal.
// Output (128 MiB) fits the 256 MiB Infinity Cache and dirty lines drain
// after kernel retirement, so cached stores may complete faster than the
// 6.3 TB/s HBM stream that NT forces.
//
// exp(-d/beta) = exp2(d * (-log2(e)/beta)); beta = 0.04
#define EXP2_SCALE (-36.06737602222409f)   // -log2(e) / 0.04

#define N_RBF      8192
#define NPAIR      (N_RBF / 2)             // 4096 float4 per b-row
#define BLOCK      256
#define ITERS      (NPAIR / BLOCK)         // 16

typedef float f32x4 __attribute__((ext_vector_type(4)));

__global__ __launch_bounds__(BLOCK) void rbf_kernel(
    const float2* __restrict__ x,        // [B]
    const float2* __restrict__ xd,       // [B]
    const f32x4* __restrict__ c4,        // [N/2] (two centres per f32x4)
    f32x4* __restrict__ out)             // [B * N/2]
{
    const int b = blockIdx.x;            // one b-row per block
    const float2 xb  = x[b];             // block-uniform -> s_load, once
    const float2 xdb = xd[b];
    const int t = threadIdx.x;
    f32x4* __restrict__ orow = out + (size_t)b * NPAIR;

    #pragma unroll 8
    for (int i = 0; i < ITERS; ++i) {
        const int nn = i * BLOCK + t;
        const f32x4 cc = c4[nn];         // coalesced 16B/lane, L2-resident

        float dx, dy;
        dx = xb.x  - cc.x;  dy = xb.y  - cc.y;  const float d00 = dx*dx + dy*dy;
        dx = xdb.x - cc.x;  dy = xdb.y - cc.y;  const float d01 = dx*dx + dy*dy;
        dx = xb.x  - cc.z;  dy = xb.y  - cc.w;  const float d10 = dx*dx + dy*dy;
        dx = xdb.x - cc.z;  dy = xdb.y - cc.w;  const float d11 = dx*dx + dy*dy;

        f32x4 o;
        o.x = __builtin_amdgcn_exp2f(d00 * EXP2_SCALE);
        o.y = __builtin_amdgcn_exp2f(d01 * EXP2_SCALE);
        o.z = __builtin_amdgcn_exp2f(d10 * EXP2_SCALE);
        o.w = __builtin_amdgcn_exp2f(d11 * EXP2_SCALE);

        orow[nn] = o;   // plain cached store: let L2/L3 absorb, drain async
    }
}

extern "C" void kernel_launch(void* const* d_in, const int* in_sizes, int n_in,
                              void* d_out, int out_size, void* d_ws, size_t ws_size,
                              hipStream_t stream) {
    const float2* x  = (const float2*)d_in[0];   // [B,2] fp32
    const float2* xd = (const float2*)d_in[1];   // [B,2] fp32
    const f32x4* c4  = (const f32x4*)d_in[2];    // [N,2] fp32 as [N/2] f32x4
    f32x4* out = (f32x4*)d_out;                  // [B,N,2] fp32 as f32x4

    const int B = in_sizes[0] / 2;               // 2048

    rbf_kernel<<<B, BLOCK, 0, stream>>>(x, xd, c4, out);
}